// Round 3
// baseline (730.867 us; speedup 1.0000x reference)
//
#include <hip/hip_runtime.h>

#define BATCH 4
#define SEQ   1024
#define HIDN  768
#define NH    12
#define HD    64
#define BHN   48   // BATCH*NH

typedef __attribute__((ext_vector_type(8))) short bf16x8;
typedef __attribute__((ext_vector_type(4))) float f32x4;

#define MFMA(a, b, c) __builtin_amdgcn_mfma_f32_16x16x32_bf16((a), (b), (c), 0, 0, 0)

__device__ inline unsigned short f2bf(float f) {
    union { float f; unsigned u; } v; v.f = f;
    unsigned r = (v.u + 0x7FFFu + ((v.u >> 16) & 1u)) >> 16;
    return (unsigned short)r;
}
__device__ inline float bf2f(unsigned short s) {
    union { unsigned u; float f; } v; v.u = ((unsigned)s) << 16;
    return v.f;
}
__device__ inline unsigned long long pack4(float a, float b, float c, float d) {
    return (unsigned long long)f2bf(a)
         | ((unsigned long long)f2bf(b) << 16)
         | ((unsigned long long)f2bf(c) << 32)
         | ((unsigned long long)f2bf(d) << 48);
}

// ---------------------------------------------------------------------------
// Kernel 1: QKV projection. C[m,n] = sum_k hidden[m,k]*W[n,k] + bias[n]
// out bf16 laid out [bh][l][d], bh = b*12 + h.
// ---------------------------------------------------------------------------
__global__ __launch_bounds__(256) void qkv_kernel(
    const float* __restrict__ hidden,
    const float* __restrict__ Wq, const float* __restrict__ bq,
    const float* __restrict__ Wk, const float* __restrict__ bk,
    const float* __restrict__ Wv, const float* __restrict__ bv,
    unsigned short* __restrict__ Qb, unsigned short* __restrict__ Kb,
    unsigned short* __restrict__ Vb)
{
    const int mt  = blockIdx.x;   // 0..31  (m tile of 128)
    const int nt  = blockIdx.y;   // 0..11  (head; n tile of 64)
    const int mat = blockIdx.z;   // 0:Q 1:K 2:V
    const float* W  = (mat == 0) ? Wq : (mat == 1) ? Wk : Wv;
    const float* bs = (mat == 0) ? bq : (mat == 1) ? bk : bv;
    unsigned short* out = (mat == 0) ? Qb : (mat == 1) ? Kb : Vb;

    const int t = threadIdx.x, lane = t & 63, wid = t >> 6;
    const int row16 = lane & 15, kg = lane >> 4;
    const int m0 = mt * 128;
    const int wm = (wid >> 1) * 64, wn = (wid & 1) * 32;

    __shared__ __align__(16) unsigned short As[128 * 40];
    __shared__ __align__(16) unsigned short Ws[64 * 40];

    f32x4 acc[4][2] = {};

    for (int k0 = 0; k0 < HIDN; k0 += 32) {
        for (int i = 0; i < 4; ++i) {
            int f4 = t + i * 256;            // 0..1023 float4s
            int r = f4 >> 3, c4 = f4 & 7;
            float4 v = *(const float4*)(hidden + (size_t)(m0 + r) * HIDN + k0 + c4 * 4);
            *(unsigned long long*)&As[r * 40 + c4 * 4] = pack4(v.x, v.y, v.z, v.w);
        }
        for (int i = 0; i < 2; ++i) {
            int f4 = t + i * 256;            // 0..511
            int r = f4 >> 3, c4 = f4 & 7;
            float4 v = *(const float4*)(W + (size_t)(nt * 64 + r) * HIDN + k0 + c4 * 4);
            *(unsigned long long*)&Ws[r * 40 + c4 * 4] = pack4(v.x, v.y, v.z, v.w);
        }
        __syncthreads();
        bf16x8 af[4], bfr[2];
        for (int mf = 0; mf < 4; ++mf)
            af[mf] = *(const bf16x8*)&As[(wm + mf * 16 + row16) * 40 + kg * 8];
        for (int nf = 0; nf < 2; ++nf)
            bfr[nf] = *(const bf16x8*)&Ws[(wn + nf * 16 + row16) * 40 + kg * 8];
        for (int mf = 0; mf < 4; ++mf)
            for (int nf = 0; nf < 2; ++nf)
                acc[mf][nf] = MFMA(af[mf], bfr[nf], acc[mf][nf]);
        __syncthreads();
    }

    const int bh = (m0 / SEQ) * NH + nt;   // m tile never straddles a batch
    for (int nf = 0; nf < 2; ++nf) {
        int d = wn + nf * 16 + row16;
        float bias_v = bs[nt * 64 + d];
        for (int mf = 0; mf < 4; ++mf)
            for (int j = 0; j < 4; ++j) {
                int m = m0 + wm + mf * 16 + kg * 4 + j;
                int l = m & (SEQ - 1);
                out[((size_t)bh * SEQ + l) * HD + d] = f2bf(acc[mf][nf][j] + bias_v);
            }
    }
}

// ---------------------------------------------------------------------------
// Kernel 2: scores[bh][l][r] = ( q.k + (q+k).sm[l,r] ) / 8 + mask[b][r]
// block: 16 l x 16 r tile, ALL 48 bh. 512 threads (8 waves), 2 blocks/CU.
// ---------------------------------------------------------------------------
__global__ __launch_bounds__(512, 4) void scores_kernel(
    const float* __restrict__ sm, const float* __restrict__ mask,
    const unsigned short* __restrict__ Qb, const unsigned short* __restrict__ Kb,
    float* __restrict__ S)
{
    const int rt = blockIdx.x, lt = blockIdx.y;
    const int r0 = rt * 16, l0 = lt * 16;
    const int t = threadIdx.x, lane = t & 63, wid = t >> 6;
    const int row16 = lane & 15, kg = lane >> 4;

    __shared__ __align__(16) unsigned short sm_s[16 * 16 * 64];    // 32 KB, swizzled
    __shared__ __align__(16) unsigned short bias_s[16 * 48 * 18];  // 27.6 KB
    __shared__ float mask_s[BATCH * 16];

    // stage sm tile 16x16x64 fp32 -> bf16 (swizzle 16B slot by (l^r)&7)
    for (int i = 0; i < 8; ++i) {
        int f4 = t + i * 512;            // 0..4095 float4s
        int l = f4 >> 8;
        int rem = f4 & 255;
        int r = rem >> 4, d4 = rem & 15;
        float4 v = *(const float4*)(sm + ((size_t)(l0 + l) * SEQ + (r0 + r)) * HD + d4 * 4);
        int idx = ((l * 16 + r) * 64 + d4 * 4) ^ (((l ^ r) & 7) << 3);
        *(unsigned long long*)&sm_s[idx] = pack4(v.x, v.y, v.z, v.w);
    }
    if (t < BATCH * 16) {
        int b = t >> 4, r = t & 15;
        mask_s[t] = mask[(size_t)b * SEQ + r0 + r];
    }
    __syncthreads();

    // phase 1: bias_q. wave handles l = wid*2 + {0,1}; out [l][bh][r].
    for (int li = 0; li < 2; ++li) {
        int l = wid * 2 + li;
        bf16x8 af[2];
        for (int kf = 0; kf < 2; ++kf) {
            int d0 = kf * 32 + kg * 8;
            af[kf] = *(const bf16x8*)&sm_s[((l * 16 + row16) * 64 + d0) ^ (((l ^ row16) & 7) << 3)];
        }
        bf16x8 bq8[3][2];
        for (int nf = 0; nf < 3; ++nf)
            for (int kf = 0; kf < 2; ++kf) {
                int bh = nf * 16 + row16, d0 = kf * 32 + kg * 8;
                bq8[nf][kf] = *(const bf16x8*)&Qb[((size_t)bh * SEQ + l0 + l) * HD + d0];
            }
        f32x4 acc[3] = {};
        for (int kf = 0; kf < 2; ++kf)
            for (int nf = 0; nf < 3; ++nf)
                acc[nf] = MFMA(af[kf], bq8[nf][kf], acc[nf]);
        for (int nf = 0; nf < 3; ++nf)
            for (int j = 0; j < 4; ++j) {
                int r = kg * 4 + j, bh = nf * 16 + row16;
                bias_s[(l * 48 + bh) * 18 + r] = f2bf(acc[nf][j]);
            }
    }
    __syncthreads();

    // phase 2: bias_k. wave handles r = wid*2 + {0,1}; += into bias_s.
    for (int ri = 0; ri < 2; ++ri) {
        int r = wid * 2 + ri;
        bf16x8 af[2];
        for (int kf = 0; kf < 2; ++kf) {
            int d0 = kf * 32 + kg * 8;
            af[kf] = *(const bf16x8*)&sm_s[((row16 * 16 + r) * 64 + d0) ^ (((row16 ^ r) & 7) << 3)];
        }
        bf16x8 bk8[3][2];
        for (int nf = 0; nf < 3; ++nf)
            for (int kf = 0; kf < 2; ++kf) {
                int bh = nf * 16 + row16, d0 = kf * 32 + kg * 8;
                bk8[nf][kf] = *(const bf16x8*)&Kb[((size_t)bh * SEQ + r0 + r) * HD + d0];
            }
        f32x4 acc[3] = {};
        for (int kf = 0; kf < 2; ++kf)
            for (int nf = 0; nf < 3; ++nf)
                acc[nf] = MFMA(af[kf], bk8[nf][kf], acc[nf]);
        for (int nf = 0; nf < 3; ++nf)
            for (int j = 0; j < 4; ++j) {
                int l = kg * 4 + j, bh = nf * 16 + row16;
                int idx = (l * 48 + bh) * 18 + r;
                bias_s[idx] = f2bf(bf2f(bias_s[idx]) + acc[nf][j]);
            }
    }
    __syncthreads();

    // phase 3: QK^T + combine. wave handles bh = wid*6 + {0..5}.
    for (int bi = 0; bi < 6; ++bi) {
        int bh = wid * 6 + bi;
        int b = bh / NH;
        bf16x8 aq[2], bkf[2];
        for (int kf = 0; kf < 2; ++kf) {
            int d0 = kf * 32 + kg * 8;
            aq[kf]  = *(const bf16x8*)&Qb[((size_t)bh * SEQ + l0 + row16) * HD + d0];
            bkf[kf] = *(const bf16x8*)&Kb[((size_t)bh * SEQ + r0 + row16) * HD + d0];
        }
        f32x4 acc = {};
        acc = MFMA(aq[0], bkf[0], acc);
        acc = MFMA(aq[1], bkf[1], acc);
        for (int j = 0; j < 4; ++j) {
            int l = kg * 4 + j, r = row16;
            float s = (acc[j] + bf2f(bias_s[(l * 48 + bh) * 18 + r])) * 0.125f
                    + mask_s[b * 16 + r];
            S[((size_t)bh * SEQ + l0 + l) * SEQ + r0 + r] = s;
        }
    }
}

// ---------------------------------------------------------------------------
// Kernel 3: fused softmax + PV. block = (bh, 16-l tile), 256 threads.
// Softmax of 16 S-rows -> swizzled LDS P tile (bf16) -> P @ V with
// double-buffered V staging. out fp32 [b][l][h*64+d].
// ---------------------------------------------------------------------------
__global__ __launch_bounds__(256, 3) void softpv_kernel(
    const float* __restrict__ S, const unsigned short* __restrict__ Vb,
    float* __restrict__ out)
{
    const int bh = blockIdx.x, lt = blockIdx.y;
    const int l0 = lt * 16;
    const int b = bh / NH, h = bh % NH;
    const int t = threadIdx.x, lane = t & 63, wid = t >> 6;   // 4 waves
    const int row16 = lane & 15, kg = lane >> 4;

    __shared__ __align__(16) unsigned short P_s[16 * 1024];   // 32 KB, swizzled
    __shared__ __align__(16) unsigned short vt[2][64 * 72];   // 2 x 9 KB, transposed V

    // softmax: wave handles rows l = wid*4 + {0..3}
    for (int li = 0; li < 4; ++li) {
        int l = wid * 4 + li;
        const float* row = S + ((size_t)bh * SEQ + l0 + l) * SEQ;
        float4 v0 = ((const float4*)row)[lane];
        float4 v1 = ((const float4*)row)[lane + 64];
        float4 v2 = ((const float4*)row)[lane + 128];
        float4 v3 = ((const float4*)row)[lane + 192];
        float m = fmaxf(fmaxf(fmaxf(v0.x, v0.y), fmaxf(v0.z, v0.w)),
                  fmaxf(fmaxf(fmaxf(v1.x, v1.y), fmaxf(v1.z, v1.w)),
                  fmaxf(fmaxf(fmaxf(v2.x, v2.y), fmaxf(v2.z, v2.w)),
                        fmaxf(fmaxf(v3.x, v3.y), fmaxf(v3.z, v3.w)))));
        for (int off = 32; off; off >>= 1) m = fmaxf(m, __shfl_xor(m, off));
        v0.x = __expf(v0.x - m); v0.y = __expf(v0.y - m); v0.z = __expf(v0.z - m); v0.w = __expf(v0.w - m);
        v1.x = __expf(v1.x - m); v1.y = __expf(v1.y - m); v1.z = __expf(v1.z - m); v1.w = __expf(v1.w - m);
        v2.x = __expf(v2.x - m); v2.y = __expf(v2.y - m); v2.z = __expf(v2.z - m); v2.w = __expf(v2.w - m);
        v3.x = __expf(v3.x - m); v3.y = __expf(v3.y - m); v3.z = __expf(v3.z - m); v3.w = __expf(v3.w - m);
        float s = (v0.x + v0.y + v0.z + v0.w) + (v1.x + v1.y + v1.z + v1.w)
                + (v2.x + v2.y + v2.z + v2.w) + (v3.x + v3.y + v3.z + v3.w);
        for (int off = 32; off; off >>= 1) s += __shfl_xor(s, off);
        float inv = 1.0f / s;
        int swz = (l & 7) << 3, base = l << 10;
        *(unsigned long long*)&P_s[base + (((lane      ) * 4) ^ swz)] = pack4(v0.x*inv, v0.y*inv, v0.z*inv, v0.w*inv);
        *(unsigned long long*)&P_s[base + (((lane +  64) * 4) ^ swz)] = pack4(v1.x*inv, v1.y*inv, v1.z*inv, v1.w*inv);
        *(unsigned long long*)&P_s[base + (((lane + 128) * 4) ^ swz)] = pack4(v2.x*inv, v2.y*inv, v2.z*inv, v2.w*inv);
        *(unsigned long long*)&P_s[base + (((lane + 192) * 4) ^ swz)] = pack4(v3.x*inv, v3.y*inv, v3.z*inv, v3.w*inv);
    }

    // stage V chunk r0 (64 rows x 64 d) transposed into vt[buf][d][r]
    // 64*64/4 = 1024 thread-items -> 4 iterations at 256 threads.
    #define STAGE_V(buf, r0v)                                                          \
        for (int i = 0; i < 4; ++i) {                                                  \
            int f4 = t + i * 256;                                                      \
            int r = f4 >> 4, c4 = f4 & 15;                                             \
            unsigned long long pk =                                                    \
                *(const unsigned long long*)&Vb[((size_t)bh * SEQ + (r0v) + r) * HD + c4 * 4]; \
            vt[buf][(c4 * 4 + 0) * 72 + r] = (unsigned short)(pk);                     \
            vt[buf][(c4 * 4 + 1) * 72 + r] = (unsigned short)(pk >> 16);               \
            vt[buf][(c4 * 4 + 2) * 72 + r] = (unsigned short)(pk >> 32);               \
            vt[buf][(c4 * 4 + 3) * 72 + r] = (unsigned short)(pk >> 48);               \
        }

    STAGE_V(0, 0)
    __syncthreads();

    f32x4 acc = {};
    for (int it = 0; it < 16; ++it) {
        if (it < 15) { STAGE_V((it + 1) & 1, (it + 1) * 64) }
        int r0 = it * 64, cur = it & 1;
        for (int kf = 0; kf < 2; ++kf) {
            int kk = r0 + kf * 32 + kg * 8;
            bf16x8 a  = *(const bf16x8*)&P_s[(row16 << 10) + (kk ^ ((row16 & 7) << 3))];
            bf16x8 bv = *(const bf16x8*)&vt[cur][(wid * 16 + row16) * 72 + kf * 32 + kg * 8];
            acc = MFMA(a, bv, acc);
        }
        __syncthreads();
    }

    for (int j = 0; j < 4; ++j) {
        int l = l0 + kg * 4 + j, d = wid * 16 + row16;
        out[((size_t)b * SEQ + l) * HIDN + h * HD + d] = acc[j];
    }
}

// ---------------------------------------------------------------------------
extern "C" void kernel_launch(void* const* d_in, const int* in_sizes, int n_in,
                              void* d_out, int out_size, void* d_ws, size_t ws_size,
                              hipStream_t stream)
{
    const float* hidden = (const float*)d_in[0];
    const float* mask   = (const float*)d_in[1];
    const float* smat   = (const float*)d_in[2];
    const float* Wq = (const float*)d_in[3];
    const float* bq = (const float*)d_in[4];
    const float* Wk = (const float*)d_in[5];
    const float* bk = (const float*)d_in[6];
    const float* Wv = (const float*)d_in[7];
    const float* bv = (const float*)d_in[8];
    float* out = (float*)d_out;

    char* ws = (char*)d_ws;
    unsigned short* Qb = (unsigned short*)(ws);                 // 6 MB
    unsigned short* Kb = (unsigned short*)(ws + 6291456);       // 6 MB
    unsigned short* Vb = (unsigned short*)(ws + 12582912);      // 6 MB
    float* S = (float*)(ws + 18874368);                         // 192 MB

    qkv_kernel<<<dim3(32, 12, 3), 256, 0, stream>>>(hidden, Wq, bq, Wk, bk, Wv, bv, Qb, Kb, Vb);
    scores_kernel<<<dim3(64, 64), 512, 0, stream>>>(smat, mask, Qb, Kb, S);
    softpv_kernel<<<dim3(BHN, 64), 256, 0, stream>>>(S, Vb, out);
}